// Round 6
// baseline (1384.888 us; speedup 1.0000x reference)
//
#include <hip/hip_runtime.h>
#include <hip/hip_bf16.h>
#include <math.h>

// MoE top-2/8: D=1024 H=4096, T=16384 tokens. Grouped-GEMM two-pass design.
// R5: both GEMMs ported to the 256x256 counted-vmcnt phase template
// (T1 XCD swizzle + T2 LDS XOR-swizzle + T3 phase split + T4 vmcnt(4) never
// drained in main loop + T5 setprio). Raw s_barrier; NO __syncthreads in the
// K-loop (its implicit vmcnt(0) drain was the R4 failure).
// (3rd submission attempt — rounds 4/5 hit infra failures; kernel has never
// actually run. Ledger/WAR/swizzle audited clean twice.)
#define T_TOK 16384
#define D_DIM 1024
#define H_DIM 4096
#define E_EXP 8
#define TOT_ROWS (T_TOK * 2)   // every token goes to exactly 2 experts
#define NBLK 64                // routing blocks

typedef __attribute__((ext_vector_type(8))) short bf16x8;
typedef __attribute__((ext_vector_type(4))) float floatx4;

__device__ __forceinline__ unsigned short f2bf(float f) {
  union { float f; unsigned u; } v; v.f = f;
  unsigned r = v.u + 0x7fffu + ((v.u >> 16) & 1u);   // RNE
  return (unsigned short)(r >> 16);
}
__device__ __forceinline__ float bf2f(unsigned short s) {
  union { unsigned u; float f; } v; v.u = ((unsigned)s) << 16;
  return v.f;
}

// async global->LDS, 16B/lane; LDS dest is wave-uniform base + lane*16
__device__ __forceinline__ void gload_lds16(const void* g, void* l) {
  __builtin_amdgcn_global_load_lds(
      (const __attribute__((address_space(1))) void*)g,
      (__attribute__((address_space(3))) void*)l, 16, 0, 0);
}

// counted vmcnt wait (N = loads allowed to stay in flight) + compiler fence
#define WAITVM(N) asm volatile("s_waitcnt vmcnt(" #N ")" ::: "memory")
// raw barrier bracketed by compiler memory fences (NOT __syncthreads: that
// would emit s_waitcnt vmcnt(0) and serialize the pipeline)
#define BAR() do { asm volatile("" ::: "memory"); \
                   __builtin_amdgcn_s_barrier(); \
                   asm volatile("" ::: "memory"); } while (0)

// ---------------- gate: fp64-accurate logits, top-2, softmax ----------------
__global__ void __launch_bounds__(256) gate_kernel(
    const float* __restrict__ x, const float* __restrict__ gw,
    const float* __restrict__ gb, int* __restrict__ eids,
    float* __restrict__ wgt)
{
  const int lane = threadIdx.x & 63;
  const int t = blockIdx.x * 4 + (threadIdx.x >> 6);   // one wave per token
  const float* xr = x + (size_t)t * D_DIM;
  double acc[E_EXP];
#pragma unroll
  for (int e = 0; e < E_EXP; ++e) acc[e] = 0.0;
  for (int j = 0; j < D_DIM / 64; ++j) {
    const int d = j * 64 + lane;                       // coalesced x read
    const double xv = (double)xr[d];
    const float* g = gw + d * E_EXP;
#pragma unroll
    for (int e = 0; e < E_EXP; ++e) acc[e] += xv * (double)g[e];
  }
#pragma unroll
  for (int e = 0; e < E_EXP; ++e) {
    double v = acc[e];
#pragma unroll
    for (int s = 32; s > 0; s >>= 1) v += __shfl_xor(v, s, 64);
    acc[e] = v;
  }
  if (lane == 0) {
    double l[E_EXP];
#pragma unroll
    for (int e = 0; e < E_EXP; ++e) l[e] = acc[e] + (double)gb[e];
    int e0 = 0;                                        // strict > : first index wins ties
    for (int e = 1; e < E_EXP; ++e) if (l[e] > l[e0]) e0 = e;
    int e1 = (e0 == 0) ? 1 : 0;
    for (int e = 0; e < E_EXP; ++e) if (e != e0 && l[e] > l[e1]) e1 = e;
    const double ex = exp(l[e1] - l[e0]);              // softmax over the 2 selected
    eids[t * 2] = e0; eids[t * 2 + 1] = e1;
    wgt[t * 2] = (float)(1.0 / (1.0 + ex));
    wgt[t * 2 + 1] = (float)(ex / (1.0 + ex));
  }
}

// ------------- routing pass 1: per-block expert histogram (LDS only) --------
__global__ void __launch_bounds__(256) hist_kernel(
    const int* __restrict__ eids, int* __restrict__ blockHist)
{
  __shared__ int h[E_EXP];
  const int tid = threadIdx.x, blk = blockIdx.x;
  if (tid < E_EXP) h[tid] = 0;
  __syncthreads();
  const int s0 = blk * (TOT_ROWS / NBLK);
  for (int i = tid; i < TOT_ROWS / NBLK; i += 256)
    atomicAdd(&h[eids[s0 + i]], 1);                    // LDS atomic: cheap
  __syncthreads();
  if (tid < E_EXP) blockHist[blk * E_EXP + tid] = h[tid];
}

// ------------- routing pass 2: serial prefix over 64x8 ints -----------------
__global__ void prefix_kernel(const int* __restrict__ blockHist,
                              int* __restrict__ blockBase, int* __restrict__ offs)
{
  if (threadIdx.x == 0) {
    int tot[E_EXP];
    for (int e = 0; e < E_EXP; ++e) {
      int s = 0;
      for (int b = 0; b < NBLK; ++b) s += blockHist[b * E_EXP + e];
      tot[e] = s;
    }
    int run = 0;
    for (int e = 0; e < E_EXP; ++e) { offs[e] = run; run += tot[e]; }
    offs[E_EXP] = run;                                 // == TOT_ROWS
    for (int e = 0; e < E_EXP; ++e) {
      int r = offs[e];
      for (int b = 0; b < NBLK; ++b) { blockBase[b * E_EXP + e] = r; r += blockHist[b * E_EXP + e]; }
    }
  }
}

// ------------- routing pass 3: assign rows + inverse map --------------------
__global__ void __launch_bounds__(256) assign_kernel(
    const int* __restrict__ eids, const float* __restrict__ wgt,
    const int* __restrict__ blockBase,
    int* __restrict__ rowmap, int* __restrict__ invrow)
{
  __shared__ int base[E_EXP];
  __shared__ int cnt[E_EXP];
  const int tid = threadIdx.x, blk = blockIdx.x;
  if (tid < E_EXP) { base[tid] = blockBase[blk * E_EXP + tid]; cnt[tid] = 0; }
  __syncthreads();
  const int s0 = blk * (TOT_ROWS / NBLK);
  for (int i = tid; i < TOT_ROWS / NBLK; i += 256) {
    const int s = s0 + i;
    const int e = eids[s];
    const int r = base[e] + atomicAdd(&cnt[e], 1);     // unique row in expert region
    rowmap[r] = s >> 1;                                // token index
    invrow[s] = r;                                     // (token,slot) -> row
  }
}

// ------------- x -> bf16 straight convert (no scatter) ----------------------
__global__ void __launch_bounds__(256) convert_x(
    const float* __restrict__ x, unsigned short* __restrict__ xb)
{
  const size_t i = (size_t)blockIdx.x * 256 + threadIdx.x;   // float4 granularity
  const float4 v = ((const float4*)x)[i];
  ushort4 o;
  o.x = f2bf(v.x); o.y = f2bf(v.y); o.z = f2bf(v.z); o.w = f2bf(v.w);
  ((ushort4*)xb)[i] = o;
}

// --------- weight transpose+convert: src fp32 [E][R][C] -> dst bf16 [E][C][R]
__global__ void __launch_bounds__(256) transpose_conv(
    const float* __restrict__ src, unsigned short* __restrict__ dst, int R, int C)
{
  __shared__ float tile[32][33];
  const int tx = threadIdx.x, ty = threadIdx.y;   // 32 x 8
  const size_t ebase = (size_t)blockIdx.z * R * C;
  const int c0 = blockIdx.x * 32, r0 = blockIdx.y * 32;
  const float* s = src + ebase;
#pragma unroll
  for (int j = 0; j < 4; ++j)
    tile[ty + j * 8][tx] = s[(size_t)(r0 + ty + j * 8) * C + c0 + tx];
  __syncthreads();
  unsigned short* d = dst + ebase;
#pragma unroll
  for (int j = 0; j < 4; ++j)
    d[(size_t)(c0 + ty + j * 8) * R + r0 + tx] = f2bf(tile[tx][ty + j * 8]);
}

__global__ void zero_kernel(float4* __restrict__ p, int n4) {
  const int i = blockIdx.x * blockDim.x + threadIdx.x;
  if (i < n4) p[i] = make_float4(0.f, 0.f, 0.f, 0.f);
}

// =================== 256x256 counted-vmcnt grouped GEMM =====================
// BM=BN=256, BK=64, 512 threads = 8 waves (2M x 4N), per-wave out 128x64.
// LDS: 2 slots x (A 32KB + B 32KB) = 128KB. Each operand stored as 2
// INTERLEAVED halves so each tile-phase (C-quadrant) first-needs a distinct
// half-tile:
//   A half h holds m-rows {h*64+[0,64), 128+h*64+[0,64)}   (16KB: 128 rows x 64k)
//   B half h holds n-rows with (n>>5)&1 == h
// Per tile t (slot S=t&1), 4 phases; phase p: WAITVM -> BAR -> stage one
// half-tile of t+1 into slot S^1 -> ds_read frags -> setprio(1) 16 MFMA.
// Stage order A0,B0,B1,A1; first-need A0@p1,B0@p1,B1@p2,A1@p3 => >=3 phases
// of flight per half-tile. vmcnt(4) at p1-p3 retires exactly the needed
// half-tile (2 loads/stage); p4 waits nothing.
// T2 swizzle byte ^= ((byte>>9)&1)<<5 : inverse-swz SOURCE (global_load_lds
// writes linearly) + swz on ds_read. Rows are 128B so bit9 = row bit2.
template<int KDIM, int NOUT, bool GATHER, bool RELU>
__global__ void __launch_bounds__(512, 2) gemm8p_kernel(
    const unsigned short* __restrict__ Amat,   // [rows][KDIM] bf16 (or xb for gather)
    const unsigned short* __restrict__ Bmat,   // [E][NOUT][KDIM] n-major bf16
    const float* __restrict__ bias,            // [E][NOUT] (RELU only)
    unsigned short* __restrict__ Out,          // [TOT][NOUT]
    const int* __restrict__ offs, const int* __restrict__ rowmap)
{
  constexpr int NT = KDIM / 64;          // K-tiles
  constexpr int NTILES = NOUT / 256;     // n-tiles
  __shared__ unsigned short Asl[2][2][8192] __attribute__((aligned(16)));
  __shared__ unsigned short Bsl[2][2][8192] __attribute__((aligned(16)));

  // XCD swizzle: group of 8 m-tiles x NTILES; consecutive blocks (round-robin
  // over 8 XCDs) share the same m-tile -> A panel L2-resident per XCD.
  const int linear = blockIdx.x;
  constexpr int GROUP = 8 * NTILES;
  const int idx = linear % GROUP;
  const int mtg = (linear / GROUP) * 8 + (idx & 7);    // 0..511
  const int nt  = idx >> 3;                            // 0..NTILES-1
  const int e  = mtg >> 6;
  const int mt = mtg & 63;
  const int row0 = offs[e];
  const int rows = offs[e + 1] - row0;
  if (mt * 256 >= rows) return;          // uniform early exit

  const int tid = threadIdx.x, wave = tid >> 6, lane = tid & 63;
  const int wm = wave >> 2, wn = wave & 3;

  // ---- staging source pointers (inverse-swizzled chunk) ----
  const int q  = tid >> 3;               // row within 64-row call group
  const int c8 = tid & 7;                // 16B chunk within 128B row
  const int sc = ((q >> 2) & 1) ? (c8 ^ 2) : c8;   // inverse st_16x32 swizzle

  const unsigned short* agp[2][2];       // [half][call]
#pragma unroll
  for (int h = 0; h < 2; ++h)
#pragma unroll
    for (int c = 0; c < 2; ++c) {
      const int m_row = c * 128 + h * 64 + q;
      if constexpr (GATHER) {
        const int r = mt * 256 + m_row;
        const int tok = rowmap[row0 + (r < rows ? r : 0)];
        agp[h][c] = Amat + (size_t)tok * KDIM + sc * 8;
      } else {
        int gr = row0 + mt * 256 + m_row;
        gr = gr < TOT_ROWS - 1 ? gr : TOT_ROWS - 1;
        agp[h][c] = Amat + (size_t)gr * KDIM + sc * 8;
      }
    }
  const unsigned short* Wb = Bmat + ((size_t)e * NOUT + nt * 256) * KDIM;
  const unsigned short* bgp[2][2];
#pragma unroll
  for (int h = 0; h < 2; ++h)
#pragma unroll
    for (int c = 0; c < 2; ++c) {
      const int n_row = c * 128 + (q >> 5) * 64 + h * 32 + (q & 31);
      bgp[h][c] = Wb + (size_t)n_row * KDIM + sc * 8;
    }

  // ---- fragment ds_read byte offsets (swizzled) ----
  int aoff[4][2], boff[2][2];
#pragma unroll
  for (int mf = 0; mf < 4; ++mf)
#pragma unroll
    for (int ks = 0; ks < 2; ++ks) {
      const int lr = wm * 64 + mf * 16 + (lane & 15);
      int b = lr * 128 + ks * 64 + (lane >> 4) * 16;
      b ^= ((b >> 9) & 1) << 5;
      aoff[mf][ks] = b;
    }
#pragma unroll
  for (int nf = 0; nf < 2; ++nf)
#pragma unroll
    for (int ks = 0; ks < 2; ++ks) {
      const int lr = wn * 32 + nf * 16 + (lane & 15);
      int b = lr * 128 + ks * 64 + (lane >> 4) * 16;
      b ^= ((b >> 9) & 1) << 5;
      boff[nf][ks] = b;
    }

  floatx4 acc[8][4];
  const floatx4 zf = {0.f, 0.f, 0.f, 0.f};
#pragma unroll
  for (int mi = 0; mi < 8; ++mi)
#pragma unroll
    for (int nj = 0; nj < 4; ++nj) acc[mi][nj] = zf;

  bf16x8 afr[4][2], bfr[2][2];

#define STG_A(D, H, KK) do { \
    gload_lds16(agp[H][0] + (KK), (char*)(&Asl[D][H][0]) + wave * 1024); \
    gload_lds16(agp[H][1] + (KK), (char*)(&Asl[D][H][0]) + 8192 + wave * 1024); \
  } while (0)
#define STG_B(D, H, KK) do { \
    gload_lds16(bgp[H][0] + (KK), (char*)(&Bsl[D][H][0]) + wave * 1024); \
    gload_lds16(bgp[H][1] + (KK), (char*)(&Bsl[D][H][0]) + 8192 + wave * 1024); \
  } while (0)
#define LDA(S, H) do { \
    _Pragma("unroll") for (int mf = 0; mf < 4; ++mf) \
    _Pragma("unroll") for (int ks = 0; ks < 2; ++ks) \
      afr[mf][ks] = *(const bf16x8*)((const char*)(&Asl[S][H][0]) + aoff[mf][ks]); \
  } while (0)
#define LDB(S, H) do { \
    _Pragma("unroll") for (int nf = 0; nf < 2; ++nf) \
    _Pragma("unroll") for (int ks = 0; ks < 2; ++ks) \
      bfr[nf][ks] = *(const bf16x8*)((const char*)(&Bsl[S][H][0]) + boff[nf][ks]); \
  } while (0)
#define MMA_Q(MS, NS) do { \
    __builtin_amdgcn_s_setprio(1); \
    _Pragma("unroll") for (int mf = 0; mf < 4; ++mf) \
    _Pragma("unroll") for (int nf = 0; nf < 2; ++nf) \
    _Pragma("unroll") for (int ks = 0; ks < 2; ++ks) \
      acc[(MS) * 4 + mf][(NS) * 2 + nf] = __builtin_amdgcn_mfma_f32_16x16x32_bf16( \
          afr[mf][ks], bfr[nf][ks], acc[(MS) * 4 + mf][(NS) * 2 + nf], 0, 0, 0); \
    __builtin_amdgcn_s_setprio(0); \
  } while (0)

// one tile in slot S, staging tile t+1 (K element offset KK) into slot S^1
#define TILE_STG(S, KK) do { \
    WAITVM(4); BAR(); STG_A((S) ^ 1, 0, KK); LDA(S, 0); LDB(S, 0); MMA_Q(0, 0); \
    WAITVM(4); BAR(); STG_B((S) ^ 1, 0, KK); LDB(S, 1);            MMA_Q(0, 1); \
    WAITVM(4); BAR(); STG_B((S) ^ 1, 1, KK); LDA(S, 1); LDB(S, 0); MMA_Q(1, 0); \
               BAR(); STG_A((S) ^ 1, 1, KK); LDB(S, 1);            MMA_Q(1, 1); \
  } while (0)
// final tile: no staging, drain counts 4 -> 2 -> 0
#define TILE_FIN(S) do { \
    WAITVM(4); BAR(); LDA(S, 0); LDB(S, 0); MMA_Q(0, 0); \
    WAITVM(2); BAR(); LDB(S, 1);            MMA_Q(0, 1); \
    WAITVM(0); BAR(); LDA(S, 1); LDB(S, 0); MMA_Q(1, 0); \
               BAR(); LDB(S, 1);            MMA_Q(1, 1); \
  } while (0)

  // prologue: stage tile 0 into slot 0 (order A0,B0,B1,A1 = steady-state order)
  STG_A(0, 0, 0); STG_B(0, 0, 0); STG_B(0, 1, 0); STG_A(0, 1, 0);

  // main: tiles in pairs (static slot indices); NT is even (16 or 64)
  for (int tp = 0; tp < NT / 2 - 1; ++tp) {
    TILE_STG(0, (2 * tp + 1) * 64);
    TILE_STG(1, (2 * tp + 2) * 64);
  }
  TILE_STG(0, (NT - 1) * 64);   // tile NT-2, stages tile NT-1 into slot 1
  TILE_FIN(1);                  // tile NT-1

#undef TILE_FIN
#undef TILE_STG
#undef MMA_Q
#undef LDB
#undef LDA
#undef STG_B
#undef STG_A

  // ---- epilogue ----
#pragma unroll
  for (int mi = 0; mi < 8; ++mi) {
    const int rbase = mt * 256 + wm * 128 + (mi >> 2) * 64 + (mi & 3) * 16 + (lane >> 4) * 4;
#pragma unroll
    for (int nj = 0; nj < 4; ++nj) {
      const int n = nt * 256 + wn * 64 + (nj >> 1) * 32 + (nj & 1) * 16 + (lane & 15);
      const floatx4 c = acc[mi][nj];
#pragma unroll
      for (int i = 0; i < 4; ++i) {
        const int r = rbase + i;
        if (r < rows) {
          float v = c[i];
          if constexpr (RELU) {
            v += bias[e * NOUT + n];
            v = v > 0.f ? v : 0.f;
          }
          Out[(size_t)(row0 + r) * NOUT + n] = f2bf(v);
        }
      }
    }
  }
}

// --------- combine: out[t] = w0*(y0+b2[e0]) + w1*(y1+b2[e1]) ----------------
__global__ void __launch_bounds__(256) combine_kernel(
    const unsigned short* __restrict__ Ybuf, const int* __restrict__ invrow,
    const int* __restrict__ eids, const float* __restrict__ wgt,
    const float* __restrict__ b2, float* __restrict__ out)
{
  const int t = blockIdx.x, tid = threadIdx.x;
  const int r0 = invrow[t * 2], r1 = invrow[t * 2 + 1];
  const int e0 = eids[t * 2], e1 = eids[t * 2 + 1];
  const float w0 = wgt[t * 2], w1 = wgt[t * 2 + 1];
  const ushort4 y0 = ((const ushort4*)(Ybuf + (size_t)r0 * D_DIM))[tid];
  const ushort4 y1 = ((const ushort4*)(Ybuf + (size_t)r1 * D_DIM))[tid];
  const float4 c0 = ((const float4*)(b2 + e0 * D_DIM))[tid];
  const float4 c1 = ((const float4*)(b2 + e1 * D_DIM))[tid];
  float4 o;
  o.x = w0 * (bf2f(y0.x) + c0.x) + w1 * (bf2f(y1.x) + c1.x);
  o.y = w0 * (bf2f(y0.y) + c0.y) + w1 * (bf2f(y1.y) + c1.y);
  o.z = w0 * (bf2f(y0.z) + c0.z) + w1 * (bf2f(y1.z) + c1.z);
  o.w = w0 * (bf2f(y0.w) + c0.w) + w1 * (bf2f(y1.w) + c1.w);
  ((float4*)(out + (size_t)t * D_DIM))[tid] = o;
}

extern "C" void kernel_launch(void* const* d_in, const int* in_sizes, int n_in,
                              void* d_out, int out_size, void* d_ws, size_t ws_size,
                              hipStream_t stream) {
  const float* x      = (const float*)d_in[0];
  const float* gate_w = (const float*)d_in[1];
  const float* gate_b = (const float*)d_in[2];
  const float* W1     = (const float*)d_in[3];
  const float* b1     = (const float*)d_in[4];
  const float* W2     = (const float*)d_in[5];
  const float* b2     = (const float*)d_in[6];
  float* out = (float*)d_out;

  char* ws = (char*)d_ws;
  const size_t MB = 1024 * 1024;
  int*   offs      = (int*)(ws + 0);                    // [9]
  int*   blockHist = (int*)(ws + 4096);                 // [64*8]
  int*   blockBase = (int*)(ws + 8192);                 // [64*8]
  int*   eids      = (int*)(ws + 16384);                // [T*2] = 128 KB
  float* wgt       = (float*)(ws + 16384 + 131072);     // [T*2]
  int*   rowmap    = (int*)(ws + 16384 + 262144);       // [TOT]
  int*   invrow    = (int*)(ws + 16384 + 393216);       // [TOT]
  unsigned short* xb   = (unsigned short*)(ws + MB);                    // 32 MB
  unsigned short* Hbuf = (unsigned short*)(ws + MB + 32 * MB);          // 256 MB
  unsigned short* W1t  = (unsigned short*)(ws + MB + (32 + 256) * MB);  // 64 MB
  unsigned short* W2t  = (unsigned short*)(ws + MB + (32 + 256 + 64) * MB); // 64 MB
  unsigned short* Ybuf = W1t;   // W1t is dead after gemm1; Ybuf overlays it (64 MB)
  const size_t need = MB + (32 + 256 + 64 + 64) * MB;

  if (ws_size < need) {  // signals ws shortage (out zeroed) without OOB writes
    zero_kernel<<<(out_size / 4 + 255) / 256, 256, 0, stream>>>((float4*)out, out_size / 4);
    return;
  }

  gate_kernel<<<T_TOK / 4, 256, 0, stream>>>(x, gate_w, gate_b, eids, wgt);
  hist_kernel<<<NBLK, 256, 0, stream>>>(eids, blockHist);
  prefix_kernel<<<1, 64, 0, stream>>>(blockHist, blockBase, offs);
  assign_kernel<<<NBLK, 256, 0, stream>>>(eids, wgt, blockBase, rowmap, invrow);
  convert_x<<<(T_TOK * D_DIM / 4) / 256, 256, 0, stream>>>(x, xb);
  transpose_conv<<<dim3(H_DIM / 32, D_DIM / 32, E_EXP), dim3(32, 8), 0, stream>>>(W1, W1t, D_DIM, H_DIM);
  transpose_conv<<<dim3(D_DIM / 32, H_DIM / 32, E_EXP), dim3(32, 8), 0, stream>>>(W2, W2t, H_DIM, D_DIM);
  // gemm1: Hbuf = relu(gather(xb) @ W1t^T + b1)   [K=1024, N=4096]
  gemm8p_kernel<D_DIM, H_DIM, true, true>
      <<<E_EXP * 64 * (H_DIM / 256), 512, 0, stream>>>(xb, W1t, b1, Hbuf, offs, rowmap);
  // gemm2: Ybuf = Hbuf @ W2t^T                    [K=4096, N=1024]
  gemm8p_kernel<H_DIM, D_DIM, false, false>
      <<<E_EXP * 64 * (D_DIM / 256), 512, 0, stream>>>(Hbuf, W2t, nullptr, Ybuf, offs, rowmap);
  combine_kernel<<<T_TOK, 256, 0, stream>>>(Ybuf, invrow, eids, wgt, b2, out);
}